// Round 5
// baseline (439.556 us; speedup 1.0000x reference)
//
#include <hip/hip_runtime.h>
#include <hip/hip_bf16.h>

// Problem constants (B=4,T=16,N=64,D=256, H=4 heads, hd=64) — all fp32 I/O
#define BATCH 64          // B*T
#define NRES 64           // N
#define DMODEL 256        // D
#define ROWS (BATCH*NRES) // 4096
#define QKVC 768          // 3*D
#define SCALE 0.125f      // 1/sqrt(64)
#define LDP 68            // padded LDS leading dim (GEMMs): 2 addrs/bank = free

// native clang vector type — accepted by __builtin_nontemporal_load
typedef float floatx4 __attribute__((ext_vector_type(4)));

// ---------------------------------------------------------------------------
// Kernel 1: qkv = x @ Wqkv + bqkv.  (4096x256)@(256x768) fp32, 64x64 tiles.
// ---------------------------------------------------------------------------
__global__ __launch_bounds__(256) void qkv_gemm(
    const float* __restrict__ x, const float* __restrict__ W,
    const float* __restrict__ bq, float* __restrict__ qkv) {
  __shared__ float As[64 * LDP];
  __shared__ float Bs[64 * LDP];
  int t = threadIdx.x;
  int tx = t & 15, ty = t >> 4;
  int rowBase = blockIdx.y * 64;
  int colBase = blockIdx.x * 64;
  float acc[4][4] = {};
  for (int kb = 0; kb < 256; kb += 64) {
#pragma unroll
    for (int p = 0; p < 4; ++p) {
      int e = (p * 256 + t) * 4;
      int r = e >> 6, c = e & 63;
      *(float4*)&As[r * LDP + c] =
          *(const float4*)&x[(size_t)(rowBase + r) * 256 + kb + c];
      *(float4*)&Bs[r * LDP + c] =
          *(const float4*)&W[(size_t)(kb + r) * QKVC + colBase + c];
    }
    __syncthreads();
#pragma unroll 4
    for (int kk = 0; kk < 64; ++kk) {
      float a[4];
      float4 b4 = *(const float4*)&Bs[kk * LDP + tx * 4];
#pragma unroll
      for (int i = 0; i < 4; ++i) a[i] = As[(ty * 4 + i) * LDP + kk];
      float b[4] = {b4.x, b4.y, b4.z, b4.w};
#pragma unroll
      for (int i = 0; i < 4; ++i)
#pragma unroll
        for (int j = 0; j < 4; ++j) acc[i][j] += a[i] * b[j];
    }
    __syncthreads();
  }
#pragma unroll
  for (int i = 0; i < 4; ++i) {
    int r = rowBase + ty * 4 + i;
#pragma unroll
    for (int j = 0; j < 4; ++j) {
      int c = colBase + tx * 4 + j;
      qkv[(size_t)r * QKVC + c] = acc[i][j] + bq[c];
    }
  }
}

// ---------------------------------------------------------------------------
// Kernel 2 (fused qk + rel + softmax + AV), one block per (b,n).
// Lane map: mi = lane>>2 (row within wave's 16), di = lane&3.
// Row m = wave*16+mi. Chunk c = 4i+di (float4 idx in the 256-f32 row):
//   - per instruction each 4-lane group covers 64B contiguous of one row,
//     16 rows per wave -> fully-consumed 64B lines (nontemporal-safe).
//   - head(c) = c/16 = i/4, lane-independent -> 4 per-head accumulators,
//     selected at compile time; NO in-loop shuffles.
// Same loop also dots the k-row (L2-hot) -> qk[h][m] for free.
// End: 2 shuffles per head per stream (16 total, once per block), logits to
// LDS, wave-per-head 64-lane softmax, AV.
// ---------------------------------------------------------------------------
__global__ __launch_bounds__(256) void attn_kernel(
    const float* __restrict__ bias, const int* __restrict__ mask,
    const float* __restrict__ qkv, float* __restrict__ ctx) {
  __shared__ float q_s[256];
  __shared__ float logit_s[256];  // [h][m]
  __shared__ float attn_s[256];   // [h][m]
  int t = threadIdx.x;
  int blk = blockIdx.x;  // b*64+n
  int b = blk >> 6;
  q_s[t] = qkv[(size_t)blk * QKVC + t];  // q = first 256 cols
  __syncthreads();
  int wave = t >> 6, lane = t & 63;
  int mi = lane >> 2, di = lane & 3;
  int m = wave * 16 + mi;
  int msk = mask[b * 64 + m];
  const floatx4* brow = (const floatx4*)(bias + (size_t)blk * 64 * 256) + m * 64 + di;
  const floatx4* krow = (const floatx4*)(qkv + (size_t)(b * 64 + m) * QKVC + 256) + di;
  const floatx4* qrow = (const floatx4*)q_s + di;
  float rel[4] = {0.f, 0.f, 0.f, 0.f};
  float pk[4]  = {0.f, 0.f, 0.f, 0.f};
#pragma unroll
  for (int i = 0; i < 16; ++i) {
    floatx4 bv = __builtin_nontemporal_load(&brow[4 * i]);
    floatx4 kv = krow[4 * i];
    floatx4 qv = qrow[4 * i];
    int h = i >> 2;  // compile-time per unrolled i
    rel[h] += bv.x * qv.x + bv.y * qv.y + bv.z * qv.z + bv.w * qv.w;
    pk[h]  += kv.x * qv.x + kv.y * qv.y + kv.z * qv.z + kv.w * qv.w;
  }
  // reduce each head's partials across the 4-lane group (di)
#pragma unroll
  for (int h = 0; h < 4; ++h) {
    rel[h] += __shfl_xor(rel[h], 1, 64);
    rel[h] += __shfl_xor(rel[h], 2, 64);
    pk[h]  += __shfl_xor(pk[h], 1, 64);
    pk[h]  += __shfl_xor(pk[h], 2, 64);
  }
  // lane di holds head di's logit for row m
  float myrel = (di == 0) ? rel[0] : (di == 1) ? rel[1] : (di == 2) ? rel[2] : rel[3];
  float mypk  = (di == 0) ? pk[0]  : (di == 1) ? pk[1]  : (di == 2) ? pk[2]  : pk[3];
  logit_s[di * 64 + m] = mypk * SCALE + (msk ? myrel * SCALE : -1e9f);
  __syncthreads();
  // softmax: wave h = head h, lane = key index m
  int h = wave, mm = lane;
  float logit = logit_s[h * 64 + mm];
  float mx = logit;
#pragma unroll
  for (int off = 32; off > 0; off >>= 1) mx = fmaxf(mx, __shfl_xor(mx, off, 64));
  float ex = __expf(logit - mx);
  float sm = ex;
#pragma unroll
  for (int off = 32; off > 0; off >>= 1) sm += __shfl_xor(sm, off, 64);
  attn_s[h * 64 + mm] = ex / sm;
  __syncthreads();
  // AV: thread t = output channel c; head = c>>6 (wave-uniform -> LDS broadcast)
  int c = t;
  int hh = c >> 6;
  float acc = 0.f;
  const float* vbase = qkv + (size_t)b * 64 * QKVC + 512 + c;
#pragma unroll 8
  for (int k = 0; k < 64; ++k) acc += attn_s[hh * 64 + k] * vbase[(size_t)k * QKVC];
  ctx[(size_t)blk * 256 + c] = acc;
}

// ---------------------------------------------------------------------------
// Kernel 3: out = ctx @ Wproj + bproj -> fp32.
// ---------------------------------------------------------------------------
__global__ __launch_bounds__(256) void proj_gemm(
    const float* __restrict__ ctx, const float* __restrict__ W,
    const float* __restrict__ bp, float* __restrict__ out) {
  __shared__ float As[64 * LDP];
  __shared__ float Bs[64 * LDP];
  int t = threadIdx.x;
  int tx = t & 15, ty = t >> 4;
  int rowBase = blockIdx.y * 64;
  int colBase = blockIdx.x * 64;
  float acc[4][4] = {};
  for (int kb = 0; kb < 256; kb += 64) {
#pragma unroll
    for (int p = 0; p < 4; ++p) {
      int e = (p * 256 + t) * 4;
      int r = e >> 6, c = e & 63;
      *(float4*)&As[r * LDP + c] =
          *(const float4*)&ctx[(size_t)(rowBase + r) * 256 + kb + c];
      *(float4*)&Bs[r * LDP + c] =
          *(const float4*)&W[(size_t)(kb + r) * 256 + colBase + c];
    }
    __syncthreads();
#pragma unroll 4
    for (int kk = 0; kk < 64; ++kk) {
      float a[4];
      float4 b4 = *(const float4*)&Bs[kk * LDP + tx * 4];
#pragma unroll
      for (int i = 0; i < 4; ++i) a[i] = As[(ty * 4 + i) * LDP + kk];
      float b[4] = {b4.x, b4.y, b4.z, b4.w};
#pragma unroll
      for (int i = 0; i < 4; ++i)
#pragma unroll
        for (int j = 0; j < 4; ++j) acc[i][j] += a[i] * b[j];
    }
    __syncthreads();
  }
#pragma unroll
  for (int i = 0; i < 4; ++i) {
    int r = rowBase + ty * 4 + i;
#pragma unroll
    for (int j = 0; j < 4; ++j) {
      int c = colBase + tx * 4 + j;
      out[(size_t)r * 256 + c] = acc[i][j] + bp[c];
    }
  }
}

extern "C" void kernel_launch(void* const* d_in, const int* in_sizes, int n_in,
                              void* d_out, int out_size, void* d_ws, size_t ws_size,
                              hipStream_t stream) {
  // setup_inputs order: x, bias_features, mask, Wqkv, bqkv, Wproj, bproj
  const float* x    = (const float*)d_in[0];
  const float* bias = (const float*)d_in[1];
  const int*   mask = (const int*)d_in[2];
  const float* Wqkv = (const float*)d_in[3];
  const float* bqkv = (const float*)d_in[4];
  const float* Wprj = (const float*)d_in[5];
  const float* bprj = (const float*)d_in[6];
  float* out = (float*)d_out;

  // workspace layout (fp32): qkv (4096x768) | ctx (4096x256)
  float* qkv_ws = (float*)d_ws;
  float* ctx_ws = qkv_ws + (size_t)ROWS * QKVC;

  qkv_gemm<<<dim3(12, 64), 256, 0, stream>>>(x, Wqkv, bqkv, qkv_ws);
  attn_kernel<<<ROWS, 256, 0, stream>>>(bias, mask, qkv_ws, ctx_ws);
  proj_gemm<<<dim3(4, 64), 256, 0, stream>>>(ctx_ws, Wprj, bprj, out);
}

// Round 6
// 410.463 us; speedup vs baseline: 1.0709x; 1.0709x over previous
//
#include <hip/hip_runtime.h>
#include <hip/hip_bf16.h>

// Problem constants (B=4,T=16,N=64,D=256, H=4 heads, hd=64) — all fp32 I/O
#define BATCH 64          // B*T
#define NRES 64           // N
#define DMODEL 256        // D
#define ROWS (BATCH*NRES) // 4096
#define QKVC 768          // 3*D
#define SCALE 0.125f      // 1/sqrt(64)
#define LDP 68            // padded LDS leading dim: b128-aligned, conflict-benign

// native clang vector type — accepted by __builtin_nontemporal_load
typedef float floatx4 __attribute__((ext_vector_type(4)));

// ---------------------------------------------------------------------------
// Kernel 1: qkv = x @ Wqkv + bqkv.  (4096x256)@(256x768) fp32, 64x64 tiles.
// A staged TRANSPOSED (AsT[c][r], stride 68) -> A-fragment = one ds_read_b128.
// ---------------------------------------------------------------------------
__global__ __launch_bounds__(256) void qkv_gemm(
    const float* __restrict__ x, const float* __restrict__ W,
    const float* __restrict__ bq, float* __restrict__ qkv) {
  __shared__ float AsT[64 * LDP];  // [c][r]
  __shared__ float Bs[64 * LDP];   // [r][c]
  int t = threadIdx.x;
  int tx = t & 15, ty = t >> 4;
  int rowBase = blockIdx.y * 64;
  int colBase = blockIdx.x * 64;
  float acc[4][4] = {};
  for (int kb = 0; kb < 256; kb += 64) {
#pragma unroll
    for (int p = 0; p < 4; ++p) {
      int e = (p * 256 + t) * 4;
      int r = e >> 6, c = e & 63;
      float4 av = *(const float4*)&x[(size_t)(rowBase + r) * 256 + kb + c];
      AsT[(c + 0) * LDP + r] = av.x;
      AsT[(c + 1) * LDP + r] = av.y;
      AsT[(c + 2) * LDP + r] = av.z;
      AsT[(c + 3) * LDP + r] = av.w;
      *(float4*)&Bs[r * LDP + c] =
          *(const float4*)&W[(size_t)(kb + r) * QKVC + colBase + c];
    }
    __syncthreads();
#pragma unroll 4
    for (int kk = 0; kk < 64; ++kk) {
      float4 a4 = *(const float4*)&AsT[kk * LDP + ty * 4];
      float4 b4 = *(const float4*)&Bs[kk * LDP + tx * 4];
      float a[4] = {a4.x, a4.y, a4.z, a4.w};
      float b[4] = {b4.x, b4.y, b4.z, b4.w};
#pragma unroll
      for (int i = 0; i < 4; ++i)
#pragma unroll
        for (int j = 0; j < 4; ++j) acc[i][j] += a[i] * b[j];
    }
    __syncthreads();
  }
#pragma unroll
  for (int i = 0; i < 4; ++i) {
    int r = rowBase + ty * 4 + i;
#pragma unroll
    for (int j = 0; j < 4; ++j) {
      int c = colBase + tx * 4 + j;
      qkv[(size_t)r * QKVC + c] = acc[i][j] + bq[c];
    }
  }
}

// ---------------------------------------------------------------------------
// Kernel 2: qk[b,h,n,m] = sum_d q[b,n,h*64+d] * k[b,m,h*64+d]  (un-scaled)
// one block per (b,h); q/k tiles in LDS padded to 65 (odd stride -> conflict-free)
// ---------------------------------------------------------------------------
__global__ __launch_bounds__(256) void qk_gemm(const float* __restrict__ qkv,
                                               float* __restrict__ qk) {
  __shared__ float qs[64 * 65];
  __shared__ float ks[64 * 65];
  int t = threadIdx.x;
  int bh = blockIdx.x;  // b*4+h
  int b = bh >> 2, h = bh & 3;
  for (int i = 0; i < 16; ++i) {
    int idx = i * 256 + t;
    int r = idx >> 6, d = idx & 63;
    qs[r * 65 + d] = qkv[(size_t)(b * 64 + r) * QKVC + h * 64 + d];
    ks[r * 65 + d] = qkv[(size_t)(b * 64 + r) * QKVC + 256 + h * 64 + d];
  }
  __syncthreads();
  int m = t & 63, nq = t >> 6;
  for (int ni = 0; ni < 16; ++ni) {
    int n = nq * 16 + ni;
    float s = 0.f;
#pragma unroll 16
    for (int d = 0; d < 64; ++d) s += qs[n * 65 + d] * ks[m * 65 + d];
    qk[((size_t)bh * 64 + n) * 64 + m] = s;  // lanes vary m -> coalesced
  }
}

// ---------------------------------------------------------------------------
// Kernel 3: per-(b,n) relational attention (round-4 structure: full-wave
// contiguous 1KB row reads — coalescing beats shuffle-removal for this
// stream-bound loop; verified by round-5 regression). Full unroll so all 16
// NT loads can issue ahead of the shuffle tails.
// ---------------------------------------------------------------------------
__global__ __launch_bounds__(256) void attn_kernel(
    const float* __restrict__ bias, const int* __restrict__ mask,
    const float* __restrict__ qkv, const float* __restrict__ qk,
    float* __restrict__ ctx) {
  __shared__ float q_s[256];
  __shared__ float rel_s[256];   // [h][m]
  __shared__ float attn_s[256];  // [h][m]
  int t = threadIdx.x;
  int blk = blockIdx.x;  // b*64+n
  int b = blk >> 6;
  int n_res = blk & 63;
  // hoist the per-thread logit inputs: start these loads before the rel loop
  int m = t & 63, h = t >> 6;
  float s_qk = qk[(((size_t)(b * 4 + h) * 64 + n_res) * 64) + m];
  int msk = mask[b * 64 + m];
  q_s[t] = qkv[(size_t)blk * QKVC + t];  // q = first 256 cols
  __syncthreads();
  int wave = t >> 6, lane = t & 63;
  int hseg = lane >> 4;  // which head this lane's channels belong to
  float4 qv = *(const float4*)&q_s[lane * 4];
  const floatx4* brow_base =
      (const floatx4*)(bias + (size_t)blk * 64 * 256);
#pragma unroll
  for (int i = 0; i < 16; ++i) {
    int mm = i * 4 + wave;
    floatx4 bv = __builtin_nontemporal_load(&brow_base[mm * 64 + lane]);
    float p = bv.x * qv.x + bv.y * qv.y + bv.z * qv.z + bv.w * qv.w;
    p += __shfl_xor(p, 1, 64);
    p += __shfl_xor(p, 2, 64);
    p += __shfl_xor(p, 4, 64);
    p += __shfl_xor(p, 8, 64);
    if ((lane & 15) == 0) rel_s[hseg * 64 + mm] = p;
  }
  __syncthreads();
  float rel = rel_s[h * 64 + m];
  float logit = s_qk * SCALE + (msk ? rel * SCALE : -1e9f);
  // wave-wide (64 lane) softmax over m
  float mx = logit;
#pragma unroll
  for (int off = 32; off > 0; off >>= 1) mx = fmaxf(mx, __shfl_xor(mx, off, 64));
  float ex = __expf(logit - mx);
  float sm = ex;
#pragma unroll
  for (int off = 32; off > 0; off >>= 1) sm += __shfl_xor(sm, off, 64);
  attn_s[h * 64 + m] = ex / sm;
  __syncthreads();
  // AV: thread t = output channel c; head = c>>6 (wave-uniform -> LDS broadcast)
  int c = t;
  int hh = c >> 6;
  float acc = 0.f;
  const float* vbase = qkv + (size_t)b * 64 * QKVC + 512 + c;
#pragma unroll 8
  for (int mm = 0; mm < 64; ++mm) acc += attn_s[hh * 64 + mm] * vbase[(size_t)mm * QKVC];
  ctx[(size_t)blk * 256 + c] = acc;
}

// ---------------------------------------------------------------------------
// Kernel 4: out = ctx @ Wproj + bproj -> fp32. Same transposed-A staging.
// ---------------------------------------------------------------------------
__global__ __launch_bounds__(256) void proj_gemm(
    const float* __restrict__ ctx, const float* __restrict__ W,
    const float* __restrict__ bp, float* __restrict__ out) {
  __shared__ float AsT[64 * LDP];
  __shared__ float Bs[64 * LDP];
  int t = threadIdx.x;
  int tx = t & 15, ty = t >> 4;
  int rowBase = blockIdx.y * 64;
  int colBase = blockIdx.x * 64;
  float acc[4][4] = {};
  for (int kb = 0; kb < 256; kb += 64) {
#pragma unroll
    for (int p = 0; p < 4; ++p) {
      int e = (p * 256 + t) * 4;
      int r = e >> 6, c = e & 63;
      float4 av = *(const float4*)&ctx[(size_t)(rowBase + r) * 256 + kb + c];
      AsT[(c + 0) * LDP + r] = av.x;
      AsT[(c + 1) * LDP + r] = av.y;
      AsT[(c + 2) * LDP + r] = av.z;
      AsT[(c + 3) * LDP + r] = av.w;
      *(float4*)&Bs[r * LDP + c] =
          *(const float4*)&W[(size_t)(kb + r) * 256 + colBase + c];
    }
    __syncthreads();
#pragma unroll 4
    for (int kk = 0; kk < 64; ++kk) {
      float4 a4 = *(const float4*)&AsT[kk * LDP + ty * 4];
      float4 b4 = *(const float4*)&Bs[kk * LDP + tx * 4];
      float a[4] = {a4.x, a4.y, a4.z, a4.w};
      float b[4] = {b4.x, b4.y, b4.z, b4.w};
#pragma unroll
      for (int i = 0; i < 4; ++i)
#pragma unroll
        for (int j = 0; j < 4; ++j) acc[i][j] += a[i] * b[j];
    }
    __syncthreads();
  }
#pragma unroll
  for (int i = 0; i < 4; ++i) {
    int r = rowBase + ty * 4 + i;
#pragma unroll
    for (int j = 0; j < 4; ++j) {
      int c = colBase + tx * 4 + j;
      out[(size_t)r * 256 + c] = acc[i][j] + bp[c];
    }
  }
}

extern "C" void kernel_launch(void* const* d_in, const int* in_sizes, int n_in,
                              void* d_out, int out_size, void* d_ws, size_t ws_size,
                              hipStream_t stream) {
  // setup_inputs order: x, bias_features, mask, Wqkv, bqkv, Wproj, bproj
  const float* x    = (const float*)d_in[0];
  const float* bias = (const float*)d_in[1];
  const int*   mask = (const int*)d_in[2];
  const float* Wqkv = (const float*)d_in[3];
  const float* bqkv = (const float*)d_in[4];
  const float* Wprj = (const float*)d_in[5];
  const float* bprj = (const float*)d_in[6];
  float* out = (float*)d_out;

  // workspace layout (fp32): qkv (4096x768) | qk (256x64x64) | ctx (4096x256)
  float* qkv_ws = (float*)d_ws;
  float* qk_ws  = qkv_ws + (size_t)ROWS * QKVC;
  float* ctx_ws = qk_ws + (size_t)BATCH * 4 * 64 * 64;

  qkv_gemm<<<dim3(12, 64), 256, 0, stream>>>(x, Wqkv, bqkv, qkv_ws);
  qk_gemm<<<256, 256, 0, stream>>>(qkv_ws, qk_ws);
  attn_kernel<<<ROWS, 256, 0, stream>>>(bias, mask, qkv_ws, qk_ws, ctx_ws);
  proj_gemm<<<dim3(4, 64), 256, 0, stream>>>(ctx_ws, Wprj, bprj, out);
}

// Round 7
// 391.214 us; speedup vs baseline: 1.1236x; 1.0492x over previous
//
#include <hip/hip_runtime.h>
#include <hip/hip_bf16.h>

// Problem constants (B=4,T=16,N=64,D=256, H=4 heads, hd=64) — all fp32 I/O
#define BATCH 64          // B*T
#define NRES 64           // N
#define DMODEL 256        // D
#define ROWS (BATCH*NRES) // 4096
#define QKVC 768          // 3*D
#define SCALE 0.125f      // 1/sqrt(64)
#define LDP 68            // padded LDS leading dim: b128-aligned, conflict-benign

// native clang vector type — accepted by __builtin_nontemporal_load
typedef float floatx4 __attribute__((ext_vector_type(4)));

// ---------------------------------------------------------------------------
// Kernel 1: qkv = x @ Wqkv + bqkv.  (4096x256)@(256x768) fp32, 64x64 tiles.
// A staged transposed (AsT[c][r], stride 68) -> A-fragment = one ds_read_b128.
// ---------------------------------------------------------------------------
__global__ __launch_bounds__(256) void qkv_gemm(
    const float* __restrict__ x, const float* __restrict__ W,
    const float* __restrict__ bq, float* __restrict__ qkv) {
  __shared__ float AsT[64 * LDP];  // [c][r]
  __shared__ float Bs[64 * LDP];   // [r][c]
  int t = threadIdx.x;
  int tx = t & 15, ty = t >> 4;
  int rowBase = blockIdx.y * 64;
  int colBase = blockIdx.x * 64;
  float acc[4][4] = {};
  for (int kb = 0; kb < 256; kb += 64) {
#pragma unroll
    for (int p = 0; p < 4; ++p) {
      int e = (p * 256 + t) * 4;
      int r = e >> 6, c = e & 63;
      float4 av = *(const float4*)&x[(size_t)(rowBase + r) * 256 + kb + c];
      AsT[(c + 0) * LDP + r] = av.x;
      AsT[(c + 1) * LDP + r] = av.y;
      AsT[(c + 2) * LDP + r] = av.z;
      AsT[(c + 3) * LDP + r] = av.w;
      *(float4*)&Bs[r * LDP + c] =
          *(const float4*)&W[(size_t)(kb + r) * QKVC + colBase + c];
    }
    __syncthreads();
#pragma unroll 4
    for (int kk = 0; kk < 64; ++kk) {
      float4 a4 = *(const float4*)&AsT[kk * LDP + ty * 4];
      float4 b4 = *(const float4*)&Bs[kk * LDP + tx * 4];
      float a[4] = {a4.x, a4.y, a4.z, a4.w};
      float b[4] = {b4.x, b4.y, b4.z, b4.w};
#pragma unroll
      for (int i = 0; i < 4; ++i)
#pragma unroll
        for (int j = 0; j < 4; ++j) acc[i][j] += a[i] * b[j];
    }
    __syncthreads();
  }
#pragma unroll
  for (int i = 0; i < 4; ++i) {
    int r = rowBase + ty * 4 + i;
#pragma unroll
    for (int j = 0; j < 4; ++j) {
      int c = colBase + tx * 4 + j;
      qkv[(size_t)r * QKVC + c] = acc[i][j] + bq[c];
    }
  }
}

// ---------------------------------------------------------------------------
// Kernel 2: qk[b,h,n,m] = sum_d q[b,n,h*64+d] * k[b,m,h*64+d]  (un-scaled)
// one block per (b,h); q/k tiles in LDS padded to 65 (odd stride -> conflict-free)
// ---------------------------------------------------------------------------
__global__ __launch_bounds__(256) void qk_gemm(const float* __restrict__ qkv,
                                               float* __restrict__ qk) {
  __shared__ float qs[64 * 65];
  __shared__ float ks[64 * 65];
  int t = threadIdx.x;
  int bh = blockIdx.x;  // b*4+h
  int b = bh >> 2, h = bh & 3;
  for (int i = 0; i < 16; ++i) {
    int idx = i * 256 + t;
    int r = idx >> 6, d = idx & 63;
    qs[r * 65 + d] = qkv[(size_t)(b * 64 + r) * QKVC + h * 64 + d];
    ks[r * 65 + d] = qkv[(size_t)(b * 64 + r) * QKVC + 256 + h * 64 + d];
  }
  __syncthreads();
  int m = t & 63, nq = t >> 6;
  for (int ni = 0; ni < 16; ++ni) {
    int n = nq * 16 + ni;
    float s = 0.f;
#pragma unroll 16
    for (int d = 0; d < 64; ++d) s += qs[n * 65 + d] * ks[m * 65 + d];
    qk[((size_t)bh * 64 + n) * 64 + m] = s;  // lanes vary m -> coalesced
  }
}

// ---------------------------------------------------------------------------
// Kernel 3: per-(b,n) relational attention. Round-4 proven structure
// (full-wave contiguous 1KB row reads, in-loop segment reduce) PLUS
// mask-skip: bias rows for masked keys m are never loaded (reference
// discards rel for mask[b,m]==0 -> logit is -1e9 regardless). ~50% of
// rows masked => ~134 MB of the 268 MB bias stream eliminated.
// Skip branch is wave-uniform (whole wave shares row m) -> no divergence.
// rel_s stays unwritten for masked rows; logit ternary never reads it.
// ---------------------------------------------------------------------------
__global__ __launch_bounds__(256) void attn_kernel(
    const float* __restrict__ bias, const int* __restrict__ mask,
    const float* __restrict__ qkv, const float* __restrict__ qk,
    float* __restrict__ ctx) {
  __shared__ float q_s[256];
  __shared__ int mask_s[64];
  __shared__ float rel_s[256];   // [h][m]
  __shared__ float attn_s[256];  // [h][m]
  int t = threadIdx.x;
  int blk = blockIdx.x;  // b*64+n
  int b = blk >> 6;
  int n_res = blk & 63;
  // hoist the per-thread logit inputs: start these loads before the rel loop
  int m = t & 63, h = t >> 6;
  float s_qk = qk[(((size_t)(b * 4 + h) * 64 + n_res) * 64) + m];
  int msk = mask[b * 64 + m];
  if (t < 64) mask_s[t] = mask[b * 64 + t];
  q_s[t] = qkv[(size_t)blk * QKVC + t];  // q = first 256 cols
  __syncthreads();
  int wave = t >> 6, lane = t & 63;
  int hseg = lane >> 4;  // which head this lane's channels belong to
  float4 qv = *(const float4*)&q_s[lane * 4];
  const floatx4* brow_base =
      (const floatx4*)(bias + (size_t)blk * 64 * 256);
#pragma unroll
  for (int i = 0; i < 16; ++i) {
    int mm = i * 4 + wave;
    if (mask_s[mm]) {  // wave-uniform: skip bias row for masked keys
      floatx4 bv = __builtin_nontemporal_load(&brow_base[mm * 64 + lane]);
      float p = bv.x * qv.x + bv.y * qv.y + bv.z * qv.z + bv.w * qv.w;
      p += __shfl_xor(p, 1, 64);
      p += __shfl_xor(p, 2, 64);
      p += __shfl_xor(p, 4, 64);
      p += __shfl_xor(p, 8, 64);
      if ((lane & 15) == 0) rel_s[hseg * 64 + mm] = p;
    }
  }
  __syncthreads();
  float rel = rel_s[h * 64 + m];
  float logit = s_qk * SCALE + (msk ? rel * SCALE : -1e9f);
  // wave-wide (64 lane) softmax over m
  float mx = logit;
#pragma unroll
  for (int off = 32; off > 0; off >>= 1) mx = fmaxf(mx, __shfl_xor(mx, off, 64));
  float ex = __expf(logit - mx);
  float sm = ex;
#pragma unroll
  for (int off = 32; off > 0; off >>= 1) sm += __shfl_xor(sm, off, 64);
  attn_s[h * 64 + m] = ex / sm;
  __syncthreads();
  // AV: thread t = output channel c; head = c>>6 (wave-uniform -> LDS broadcast)
  int c = t;
  int hh = c >> 6;
  float acc = 0.f;
  const float* vbase = qkv + (size_t)b * 64 * QKVC + 512 + c;
#pragma unroll 8
  for (int mm = 0; mm < 64; ++mm) acc += attn_s[hh * 64 + mm] * vbase[(size_t)mm * QKVC];
  ctx[(size_t)blk * 256 + c] = acc;
}

// ---------------------------------------------------------------------------
// Kernel 4: out = ctx @ Wproj + bproj -> fp32. Transposed-A staging.
// ---------------------------------------------------------------------------
__global__ __launch_bounds__(256) void proj_gemm(
    const float* __restrict__ ctx, const float* __restrict__ W,
    const float* __restrict__ bp, float* __restrict__ out) {
  __shared__ float AsT[64 * LDP];
  __shared__ float Bs[64 * LDP];
  int t = threadIdx.x;
  int tx = t & 15, ty = t >> 4;
  int rowBase = blockIdx.y * 64;
  int colBase = blockIdx.x * 64;
  float acc[4][4] = {};
  for (int kb = 0; kb < 256; kb += 64) {
#pragma unroll
    for (int p = 0; p < 4; ++p) {
      int e = (p * 256 + t) * 4;
      int r = e >> 6, c = e & 63;
      float4 av = *(const float4*)&ctx[(size_t)(rowBase + r) * 256 + kb + c];
      AsT[(c + 0) * LDP + r] = av.x;
      AsT[(c + 1) * LDP + r] = av.y;
      AsT[(c + 2) * LDP + r] = av.z;
      AsT[(c + 3) * LDP + r] = av.w;
      *(float4*)&Bs[r * LDP + c] =
          *(const float4*)&W[(size_t)(kb + r) * 256 + colBase + c];
    }
    __syncthreads();
#pragma unroll 4
    for (int kk = 0; kk < 64; ++kk) {
      float4 a4 = *(const float4*)&AsT[kk * LDP + ty * 4];
      float4 b4 = *(const float4*)&Bs[kk * LDP + tx * 4];
      float a[4] = {a4.x, a4.y, a4.z, a4.w};
      float b[4] = {b4.x, b4.y, b4.z, b4.w};
#pragma unroll
      for (int i = 0; i < 4; ++i)
#pragma unroll
        for (int j = 0; j < 4; ++j) acc[i][j] += a[i] * b[j];
    }
    __syncthreads();
  }
#pragma unroll
  for (int i = 0; i < 4; ++i) {
    int r = rowBase + ty * 4 + i;
#pragma unroll
    for (int j = 0; j < 4; ++j) {
      int c = colBase + tx * 4 + j;
      out[(size_t)r * 256 + c] = acc[i][j] + bp[c];
    }
  }
}

extern "C" void kernel_launch(void* const* d_in, const int* in_sizes, int n_in,
                              void* d_out, int out_size, void* d_ws, size_t ws_size,
                              hipStream_t stream) {
  // setup_inputs order: x, bias_features, mask, Wqkv, bqkv, Wproj, bproj
  const float* x    = (const float*)d_in[0];
  const float* bias = (const float*)d_in[1];
  const int*   mask = (const int*)d_in[2];
  const float* Wqkv = (const float*)d_in[3];
  const float* bqkv = (const float*)d_in[4];
  const float* Wprj = (const float*)d_in[5];
  const float* bprj = (const float*)d_in[6];
  float* out = (float*)d_out;

  // workspace layout (fp32): qkv (4096x768) | qk (256x64x64) | ctx (4096x256)
  float* qkv_ws = (float*)d_ws;
  float* qk_ws  = qkv_ws + (size_t)ROWS * QKVC;
  float* ctx_ws = qk_ws + (size_t)BATCH * 4 * 64 * 64;

  qkv_gemm<<<dim3(12, 64), 256, 0, stream>>>(x, Wqkv, bqkv, qkv_ws);
  qk_gemm<<<256, 256, 0, stream>>>(qkv_ws, qk_ws);
  attn_kernel<<<ROWS, 256, 0, stream>>>(bias, mask, qkv_ws, qk_ws, ctx_ws);
  proj_gemm<<<dim3(4, 64), 256, 0, stream>>>(ctx_ws, Wprj, bprj, out);
}